// Round 14
// baseline (2508.898 us; speedup 1.0000x reference)
//
#include <hip/hip_runtime.h>
#include <math.h>

#define DEV __device__ __forceinline__

// ---- problem constants ----
#define PP    256          // pairs
#define BIMG  16
#define HB    712          // bilinear dim
#define KBIL  (712*712)    // 506944
#define KSTEPS (KBIL/32)   // 15842
#define DRELC 1936
#define BILSPLIT 61
#define BILCH   260        // ceil(15842/61); every chunk has EVEN step count (260/242)

// ---- d_out layout (floats) ----
#define SZ_ACT    (16*157)
#define OFF_ACT   0
#define OFF_POOLED (SZ_ACT)
#define SZ_POOLED (16*1936)
#define OFF_MEM   (OFF_POOLED + SZ_POOLED)
#define SZ_MEM    (24*16*1936)
#define OFF_MASK  (OFF_MEM + SZ_MEM)
#define SZ_MASK   (16*24)

// ---- ws layout (floats) ----
#define OFF_S     0
#define OFF_O     (OFF_S + 256*712)
#define OFF_Z1    (OFF_O + 256*712)
#define OFF_BIL   (OFF_Z1 + 256*712)
#define OFF_REL   (OFF_BIL + 256*712)
#define OFF_UBUF  (OFF_REL + 256*1936)
#define OFF_XP    (OFF_UBUF + 12544*256)
#define OFF_SHARED (OFF_XP + 256*128*49)
#define OFF_X1    OFF_SHARED                       // 256*128*196 floats
#define OFF_PVR   OFF_SHARED                       // 32*256*512 = 4.19M <= 6.42M
// pbil (61*256*712 = 11.12M floats) aliases ubuf+xp+shared (11.24M), all dead
// by the time the bilinear runs. lin/proj partials alias OFF_UBUF too,
// consumed by their reduce before pbil is written (stream-ordered).
#define OFF_PBIL  OFF_UBUF
#define OFF_PLIN  OFF_UBUF
#define OFF_PPROJ OFF_UBUF
#define SZ_SHARED (256*128*196)                    // max(x1, pvr)
#define OFF_INTS  (OFF_SHARED + SZ_SHARED)
// bilinear prep buffers: o as bf16 [256][712], sT f32 [712][256]
#define OFF_OB    (OFF_INTS + 256)                 // 256*712 bf16 = 91136 floats
#define OFF_ST    (OFF_OB + 91136)                 // 712*256 floats

typedef __bf16 bf16x8 __attribute__((ext_vector_type(8)));
typedef float  f32x4  __attribute__((ext_vector_type(4)));

// ============================================================
// prep: o -> bf16 (row-major [256][712]); s -> transposed sT [712][256].
// ============================================================
__global__ __launch_bounds__(256) void prep_k(const float* __restrict__ s,
    const float* __restrict__ o, __bf16* __restrict__ ob, float* __restrict__ sT) {
  int i = blockIdx.x*256 + threadIdx.x;
  if (i < 256*712) {
    ob[i] = (__bf16)o[i];
  } else {
    int j = i - 256*712;
    if (j < 712*256) {
      int h = j >> 8, n = j & 255;
      sT[j] = s[n*712 + h];
    }
  }
}

// ============================================================
// Bilinear — BARRIER-FREE, LDS-FREE. Each wave independently owns a
// 64-row x 32-col output tile of one (col-tile, row-block, k-chunk):
//   - W read per-lane DIRECTLY from global in MFMA B-frag layout
//     (col = c0+cf*16+(lane&15), k = (lane>>4)*8), depth-2 register
//     prefetch: cvt slot -> refill slot -> compute (2-step slack).
//   - A = s[n,h]*o[n,t] built per rowfrag from pre-converted bf16 o
//     (L2-resident) + sT (coalesced); consumed immediately by 2 MFMA.
//   - 1-term bf16 (r12-proven tolerance), acc[4][2] f32x4 = 32 VGPR.
// No __shared__, no s_barrier anywhere: waves slip freely; the in-order
// vmcnt queue is per-wave and never force-drained.
// Grid (12, 2, 61) x 4 waves; launch_bounds(256,3) -> VGPR cap 168.
// ============================================================
struct W4 { float4 a, b, c, d; };

__global__ __launch_bounds__(256, 3) void bil_mfma_k(
    const __bf16* __restrict__ ob, const float* __restrict__ sT,
    const float* __restrict__ W, float* __restrict__ part) {
  const int tid = threadIdx.x;
  const int wv = tid >> 6, lane = tid & 63;
  const int lr = lane & 15, lg = lane >> 4;
  const int C0 = blockIdx.x * 64;
  const int rowBase = blockIdx.y * 128;
  const int z0 = blockIdx.z * BILCH;
  const int zEnd = min(KSTEPS, z0 + BILCH);
  const int rowHalf = wv >> 1, colHalf = wv & 1;
  const int n0 = rowBase + rowHalf * 64;          // wave rows: n0 + rf*16 + ...
  const int c0 = C0 + colHalf * 32;               // wave cols: c0 + cf*16 + lr
  const int myc0 = c0 + lr, myc1 = c0 + 16 + lr;
  const bool ok0 = (myc0 < 712), ok1 = (myc1 < 712);
  const float* wp0 = W + (size_t)(ok0 ? myc0 : 711) * KBIL + lg * 8;
  const float* wp1 = W + (size_t)(ok1 ? myc1 : 711) * KBIL + lg * 8;
  const float4 z4 = make_float4(0.f, 0.f, 0.f, 0.f);

  f32x4 acc[4][2];
  #pragma unroll
  for (int rf = 0; rf < 4; rf++)
    #pragma unroll
    for (int cf = 0; cf < 2; cf++) { acc[rf][cf][0]=0.f; acc[rf][cf][1]=0.f; acc[rf][cf][2]=0.f; acc[rf][cf][3]=0.f; }

  auto wload = [&](int z, W4& w) {
    const float* p0 = wp0 + (size_t)z * 32;
    const float* p1 = wp1 + (size_t)z * 32;
    float4 a = *(const float4*)p0, b = *(const float4*)(p0 + 4);
    float4 c = *(const float4*)p1, d = *(const float4*)(p1 + 4);
    w.a = ok0 ? a : z4; w.b = ok0 ? b : z4;
    w.c = ok1 ? c : z4; w.d = ok1 ? d : z4;
  };
  auto wcvt = [&](const W4& w, bf16x8& b0, bf16x8& b1) {
    float t0[8] = {w.a.x,w.a.y,w.a.z,w.a.w, w.b.x,w.b.y,w.b.z,w.b.w};
    float t1[8] = {w.c.x,w.c.y,w.c.z,w.c.w, w.d.x,w.d.y,w.d.z,w.d.w};
    #pragma unroll
    for (int i = 0; i < 8; i++) { b0[i] = (__bf16)t0[i]; b1[i] = (__bf16)t1[i]; }
  };
  auto astep = [&](int z, bf16x8 b0, bf16x8 b1) {
    const int kk = z * 32 + lg * 8;
    const int h = kk / 712;
    const int t = kk - h * 712;                   // multiple of 8, <= 704 (712%8==0)
    #pragma unroll
    for (int rf = 0; rf < 4; rf++) {
      const int n = n0 + rf*16 + lr;
      bf16x8 o8 = *(const bf16x8*)&ob[(size_t)n * 712 + t];
      const float sv = sT[h * 256 + n];
      bf16x8 a8;
      #pragma unroll
      for (int i = 0; i < 8; i++) a8[i] = (__bf16)(sv * (float)o8[i]);
      acc[rf][0] = __builtin_amdgcn_mfma_f32_16x16x32_bf16(a8, b0, acc[rf][0], 0, 0, 0);
      acc[rf][1] = __builtin_amdgcn_mfma_f32_16x16x32_bf16(a8, b1, acc[rf][1], 0, 0, 0);
    }
  };

  // depth-2 rotating slots; (zEnd - z0) is always even (260 or 242)
  W4 wA, wB;
  wload(z0, wA);
  wload(min(z0 + 1, zEnd - 1), wB);
  for (int z = z0; z + 1 < zEnd; z += 2) {
    bf16x8 b0, b1;
    wcvt(wA, b0, b1);                  // waits only on wA (issued 2 steps ago)
    wload(min(z + 2, zEnd - 1), wA);   // refill before compute
    astep(z, b0, b1);
    wcvt(wB, b0, b1);
    wload(min(z + 3, zEnd - 1), wB);
    astep(z + 1, b0, b1);
  }

  // ---- epilogue: partials [bz][256][712] (D: col=lane&15, row=(lane>>4)*4+i)
  const int bz = blockIdx.z;
  #pragma unroll
  for (int cf = 0; cf < 2; cf++) {
    const int c = c0 + cf*16 + lr;
    if (c >= 712) continue;
    #pragma unroll
    for (int rf = 0; rf < 4; rf++) {
      #pragma unroll
      for (int i = 0; i < 4; i++) {
        const int n = n0 + rf*16 + lg*4 + i;
        part[((size_t)bz*256 + n)*712 + c] = acc[rf][cf][i];
      }
    }
  }
}

struct GP {
  const float* A; const float* A2; const float* B; const float* bias;
  float* C;
  const int* gidx; int goff;
  int M, N, K;
  int ldc, coff;
  int kChunk;
  const float* bn_g; const float* bn_b; const float* bn_m; const float* bn_v;
  const float* B2; const float* bias2; float* C2;   // mode 0 pair-merge
};

// modes:
// 0: A gathered via gidx col=blockIdx.z; B/bias/C selected by blockIdx.z
// 2: plain A (ubuf rows), plain B (vr_w)        epi: partial C[z][M][N]
// 3: A = concat(s,o)                            epi: partial C[z][M][N]
// 4: A = relu(concat(z1,bil))                   epi: partial C[z][M][N]
// 5: A = union_feat gather [(n,q)][ic]          epi: +bias -> ubuf[n][oc][q]
// 6: A = im2col(xp) 3x3 pad1                    epi: bn2(relu(+bias)) += ubuf[n][oc][q]
// 8: plain A                                    epi: sigmoid(+bias) -> C

template<int MODE>
DEV float loadA(const GP& p, int r, int k) {
  if (MODE == 0) { int fr = p.gidx[2*r + (int)blockIdx.z]; return p.A[fr*2048 + k]; }
  if (MODE == 2 || MODE == 8) return p.A[r*p.K + k];
  if (MODE == 3) return (k < 712) ? p.A[r*712 + k] : p.A2[r*712 + (k-712)];
  if (MODE == 4) { float v = (k < 712) ? p.A[r*712 + k] : p.A2[r*712 + (k-712)];
                   return fmaxf(v, 0.f); }
  if (MODE == 5) { int n = r/49, q = r - n*49; return p.A[(n*1024 + k)*49 + q]; }
  if (MODE == 6) {
    int n = r/49, q = r - n*49; int py = q/7, px = q - py*7;
    int ic = k/9, k9 = k - ic*9; int dy = k9/3, dx = k9 - dy*3;
    int iy = py + dy - 1, ix = px + dx - 1;
    if ((unsigned)iy >= 7u || (unsigned)ix >= 7u) return 0.f;
    return p.A[(n*128 + ic)*49 + iy*7 + ix];
  }
  return 0.f;
}

template<int MODE>
DEV float loadB(const GP& p, int c, int k) {
  if (MODE == 0) { const float* Bp = blockIdx.z ? p.B2 : p.B; return Bp[c*p.K + k]; }
  return p.B[c*p.K + k];
}

// ============================================================
// Generic GEMM, bf16-split MFMA (3-term, unchanged from r10-r13).
// ============================================================
template<int MODE>
__global__ __launch_bounds__(256) void gemm_k(GP p) {
  __shared__ __align__(16) __bf16 Ash[2][64*44];
  __shared__ __align__(16) __bf16 Bsh[2][64*44];
  const int tid = threadIdx.x;
  const int srow = tid & 63, koff = (tid >> 6) * 8;
  const int col0 = blockIdx.x * 64, row0 = blockIdx.y * 64;
  const int kStart = (MODE == 0) ? 0 : blockIdx.z * p.kChunk;
  const int kEnd = min(p.K, kStart + p.kChunk);
  const int wv = tid >> 6, lane = tid & 63;
  const int lr = lane & 15, lg = lane >> 4;
  const int rh = wv >> 1, ch = wv & 1;

  f32x4 acc[2][2];
  #pragma unroll
  for (int a = 0; a < 2; a++)
    #pragma unroll
    for (int b = 0; b < 2; b++) { acc[a][b][0]=0.f; acc[a][b][1]=0.f; acc[a][b][2]=0.f; acc[a][b][3]=0.f; }

  for (int kb = kStart; kb < kEnd; kb += 32) {
    {
      const int gr = row0 + srow;
      float v[8];
      #pragma unroll
      for (int i = 0; i < 8; i++) {
        const int gk = kb + koff + i;
        v[i] = (gr < p.M && gk < kEnd) ? loadA<MODE>(p, gr, gk) : 0.f;
      }
      bf16x8 hi, lo;
      #pragma unroll
      for (int i = 0; i < 8; i++) {
        __bf16 h = (__bf16)v[i];
        hi[i] = h;
        lo[i] = (__bf16)(v[i] - (float)h);
      }
      *(bf16x8*)&Ash[0][srow*44 + koff] = hi;
      *(bf16x8*)&Ash[1][srow*44 + koff] = lo;
    }
    {
      const int gc = col0 + srow;
      float v[8];
      #pragma unroll
      for (int i = 0; i < 8; i++) {
        const int gk = kb + koff + i;
        v[i] = (gc < p.N && gk < kEnd) ? loadB<MODE>(p, gc, gk) : 0.f;
      }
      bf16x8 hi, lo;
      #pragma unroll
      for (int i = 0; i < 8; i++) {
        __bf16 h = (__bf16)v[i];
        hi[i] = h;
        lo[i] = (__bf16)(v[i] - (float)h);
      }
      *(bf16x8*)&Bsh[0][srow*44 + koff] = hi;
      *(bf16x8*)&Bsh[1][srow*44 + koff] = lo;
    }
    __syncthreads();
    #pragma unroll
    for (int rf = 0; rf < 2; rf++) {
      bf16x8 ahi = *(const bf16x8*)&Ash[0][(rh*32 + rf*16 + lr)*44 + lg*8];
      bf16x8 alo = *(const bf16x8*)&Ash[1][(rh*32 + rf*16 + lr)*44 + lg*8];
      #pragma unroll
      for (int cf = 0; cf < 2; cf++) {
        bf16x8 bhi = *(const bf16x8*)&Bsh[0][(ch*32 + cf*16 + lr)*44 + lg*8];
        bf16x8 blo = *(const bf16x8*)&Bsh[1][(ch*32 + cf*16 + lr)*44 + lg*8];
        acc[rf][cf] = __builtin_amdgcn_mfma_f32_16x16x32_bf16(ahi, bhi, acc[rf][cf], 0, 0, 0);
        acc[rf][cf] = __builtin_amdgcn_mfma_f32_16x16x32_bf16(ahi, blo, acc[rf][cf], 0, 0, 0);
        acc[rf][cf] = __builtin_amdgcn_mfma_f32_16x16x32_bf16(alo, bhi, acc[rf][cf], 0, 0, 0);
      }
    }
    __syncthreads();
  }

  // ---- epilogue (D: col=lane&15, row=(lane>>4)*4+i) ----
  #pragma unroll
  for (int rf = 0; rf < 2; rf++) {
    #pragma unroll
    for (int cf = 0; cf < 2; cf++) {
      const int c = col0 + ch*32 + cf*16 + lr;
      if (c >= p.N) continue;
      #pragma unroll
      for (int i = 0; i < 4; i++) {
        const int r = row0 + rh*32 + rf*16 + lg*4 + i;
        if (r >= p.M) continue;
        float v = acc[rf][cf][i];
        if (MODE == 2 || MODE == 3 || MODE == 4) {
          p.C[(size_t)blockIdx.z * p.M * p.N + (size_t)r * p.N + c] = v;
        } else if (MODE == 5) {
          int n = r/49, q = r - n*49;
          p.C[n*12544 + c*49 + q] = v + p.bias[c];
        } else if (MODE == 6) {
          int n = r/49, q = r - n*49;
          float sc = p.bn_g[c] / sqrtf(p.bn_v[c] + 1e-5f);
          float sh = p.bn_b[c] - p.bn_m[c]*sc;
          float t2 = fmaxf(v + p.bias[c], 0.f)*sc + sh;
          p.C[n*12544 + c*49 + q] += t2;
        } else if (MODE == 8) {
          float t2 = v + p.bias[c];
          p.C[r*p.ldc + p.coff + c] = 1.f/(1.f + expf(-t2));
        } else {  // MODE 0: pair-merged subj/obj
          const float* bb = blockIdx.z ? p.bias2 : p.bias;
          float* Cp = blockIdx.z ? p.C2 : p.C;
          Cp[r*p.ldc + p.coff + c] = v + bb[c];
        }
      }
    }
  }
}

__global__ __launch_bounds__(256) void reduce_k(const float* __restrict__ part,
    const float* __restrict__ bias, float* __restrict__ out,
    int S, int MN, int N, int ldc, int coff) {
  int i = blockIdx.x*256 + threadIdx.x;
  if (i >= MN) return;
  float s = 0.f;
  for (int z = 0; z < S; z++) s += part[(size_t)z*MN + i];
  int r = i / N, c = i - r*N;
  out[r*ldc + coff + c] = s + bias[c];
}

__global__ __launch_bounds__(256) void emb_k(const int* __restrict__ pi,
    const int* __restrict__ labels, const float* __restrict__ e1,
    const float* __restrict__ e2, float* __restrict__ s, float* __restrict__ o) {
  int i = blockIdx.x*256 + threadIdx.x;
  if (i >= 2*256*200) return;
  int which = i / (256*200); int rest = i - which*(256*200);
  int n = rest / 200; int j = rest - n*200;
  int lab = labels[pi[2*n + which]];
  float v = which ? e2[lab*200 + j] : e1[lab*200 + j];
  (which ? o : s)[n*712 + 512 + j] = v;
}

__global__ __launch_bounds__(256) void conv1_k(const float* __restrict__ in,
    const float* __restrict__ w, const float* __restrict__ bias,
    const float* __restrict__ g, const float* __restrict__ bt,
    const float* __restrict__ m, const float* __restrict__ vv,
    float* __restrict__ out) {
  int idx = blockIdx.x*256 + threadIdx.x;
  if (idx >= 256*128*14) return;
  int oy = idx % 14; int t = idx / 14; int c = t & 127; int n = t >> 7;
  float acc[14];
  float b0 = bias[c];
  #pragma unroll
  for (int ox = 0; ox < 14; ox++) acc[ox] = b0;
  for (int ci = 0; ci < 2; ci++) {
    #pragma unroll
    for (int ky = 0; ky < 7; ky++) {
      int iy = oy*2 - 3 + ky;
      if ((unsigned)iy >= 27u) continue;
      const float* ir = in + ((n*2 + ci)*27 + iy)*27;
      const float* wr = w + ((c*2 + ci)*7 + ky)*7;
      float iv[27];
      #pragma unroll
      for (int x = 0; x < 27; x++) iv[x] = ir[x];
      float wk[7];
      #pragma unroll
      for (int kx = 0; kx < 7; kx++) wk[kx] = wr[kx];
      #pragma unroll
      for (int kx = 0; kx < 7; kx++)
        #pragma unroll
        for (int ox = 0; ox < 14; ox++) {
          int ix = ox*2 - 3 + kx;
          if (ix >= 0 && ix < 27) acc[ox] += iv[ix]*wk[kx];
        }
    }
  }
  float sc = g[c] / sqrtf(vv[c] + 1e-5f);
  float sh = bt[c] - m[c]*sc;
  float* orow = out + ((n*128 + c)*14 + oy)*14;
  #pragma unroll
  for (int ox = 0; ox < 14; ox++) orow[ox] = fmaxf(acc[ox], 0.f)*sc + sh;
}

__global__ __launch_bounds__(256) void pool_k(const float* __restrict__ x1,
                                              float* __restrict__ xp) {
  int idx = blockIdx.x*256 + threadIdx.x;
  if (idx >= 256*128*49) return;
  int px = idx % 7; int t = idx / 7; int py = t % 7; t /= 7;
  int c = t & 127; int n = t >> 7;
  float mx = -INFINITY;
  for (int dy = 0; dy < 3; dy++) {
    int y = py*2 - 1 + dy;
    if ((unsigned)y >= 14u) continue;
    for (int dx = 0; dx < 3; dx++) {
      int x = px*2 - 1 + dx;
      if ((unsigned)x >= 14u) continue;
      mx = fmaxf(mx, x1[((n*128 + c)*14 + y)*14 + x]);
    }
  }
  xp[((n*128 + c)*7 + py)*7 + px] = mx;
}

__global__ __launch_bounds__(256) void seg_k(const int* __restrict__ im,
    int* __restrict__ counts, int* __restrict__ starts, int* __restrict__ pos) {
  __shared__ int c[16], s[16];
  int tid = threadIdx.x;
  if (tid < 16) c[tid] = 0;
  __syncthreads();
  atomicAdd(&c[im[tid]], 1);
  __syncthreads();
  if (tid == 0) { int run = 0; for (int b = 0; b < 16; b++) { s[b] = run; run += c[b]; } }
  __syncthreads();
  if (tid < 16) { counts[tid] = c[tid]; starts[tid] = s[tid]; }
  pos[tid] = tid - s[im[tid]];
}

__global__ __launch_bounds__(256) void zeromask_k(float* __restrict__ out,
                                                  const int* __restrict__ counts) {
  int i = blockIdx.x*256 + threadIdx.x;
  if (i < SZ_MEM) { out[OFF_MEM + i] = 0.f; return; }
  int j = i - SZ_MEM;
  if (j < SZ_MASK) {
    int b = j / 24, l = j - b*24;
    out[OFF_MASK + j] = (l >= counts[b]) ? 1.f : 0.f;
  }
}

__global__ __launch_bounds__(256) void scatter_k(const float* __restrict__ rel,
    const int* __restrict__ pos, const int* __restrict__ im, float* __restrict__ out) {
  int n = blockIdx.x;
  int l = pos[n], b = im[n];
  float* dst = out + OFF_MEM + ((size_t)l*16 + b)*1936;
  const float* src = rel + (size_t)n*1936;
  for (int d = threadIdx.x; d < 1936; d += 256) dst[d] = src[d];
}

__global__ __launch_bounds__(256) void pooled_k(const float* __restrict__ rel,
    const int* __restrict__ starts, const int* __restrict__ counts,
    float* __restrict__ out) {
  int b = blockIdx.y;
  int d = blockIdx.x*256 + threadIdx.x;
  if (d >= 1936) return;
  int st = starts[b], ct = counts[b];
  float mx = -INFINITY;
  for (int i = 0; i < ct; i++) mx = fmaxf(mx, rel[(size_t)(st + i)*1936 + d]);
  out[OFF_POOLED + b*1936 + d] = mx;
}

extern "C" void kernel_launch(void* const* d_in, const int* in_sizes, int n_in,
                              void* d_out, int out_size, void* d_ws, size_t ws_size,
                              hipStream_t stream) {
  const float* features   = (const float*)d_in[0];
  const int*   pair_idx   = (const int*)d_in[1];
  const int*   im_idx     = (const int*)d_in[2];
  const int*   labels     = (const int*)d_in[3];
  const float* union_feat = (const float*)d_in[4];
  const float* spatial    = (const float*)d_in[5];
  const float* w_union    = (const float*)d_in[6];
  const float* b_union    = (const float*)d_in[7];
  const float* conv1_w    = (const float*)d_in[8];
  const float* conv1_b    = (const float*)d_in[9];
  const float* bn1_g      = (const float*)d_in[10];
  const float* bn1_b      = (const float*)d_in[11];
  const float* bn1_m      = (const float*)d_in[12];
  const float* bn1_v      = (const float*)d_in[13];
  const float* conv2_w    = (const float*)d_in[14];
  const float* conv2_b    = (const float*)d_in[15];
  const float* bn2_g      = (const float*)d_in[16];
  const float* bn2_b      = (const float*)d_in[17];
  const float* bn2_m      = (const float*)d_in[18];
  const float* bn2_v      = (const float*)d_in[19];
  const float* subj_w     = (const float*)d_in[20];
  const float* subj_b     = (const float*)d_in[21];
  const float* obj_w      = (const float*)d_in[22];
  const float* obj_b      = (const float*)d_in[23];
  const float* vr_w       = (const float*)d_in[24];
  const float* vr_b       = (const float*)d_in[25];
  const float* emb1       = (const float*)d_in[26];
  const float* emb2       = (const float*)d_in[27];
  const float* bil_w      = (const float*)d_in[28];
  const float* bil_b      = (const float*)d_in[29];
  const float* lin_w      = (const float*)d_in[30];
  const float* lin_b      = (const float*)d_in[31];
  const float* proj_w     = (const float*)d_in[32];
  const float* proj_b     = (const float*)d_in[33];
  const float* ac_w       = (const float*)d_in[34];
  const float* ac_b       = (const float*)d_in[35];

  float* ws = (float*)d_ws;
  float* s_mat  = ws + OFF_S;
  float* o_mat  = ws + OFF_O;
  float* z1     = ws + OFF_Z1;
  float* bilbuf = ws + OFF_BIL;
  float* rel    = ws + OFF_REL;
  float* ubuf   = ws + OFF_UBUF;   // layout [n][oc][q] = [256][256][49]
  float* x1     = ws + OFF_X1;
  float* xp     = ws + OFF_XP;
  float* pvr    = ws + OFF_PVR;
  float* pbil   = ws + OFF_PBIL;
  float* plin   = ws + OFF_PLIN;
  float* pproj  = ws + OFF_PPROJ;
  int*   ints   = (int*)(ws + OFF_INTS);
  __bf16* obp   = (__bf16*)(ws + OFF_OB);
  float* sTp    = ws + OFF_ST;
  int* counts = ints; int* starts = ints + 16; int* pos = ints + 32;
  float* out = (float*)d_out;

  dim3 blk(256);

  // subj + obj linears in ONE dispatch (blockIdx.z selects weights/output)
  {
    GP g{}; g.A = features; g.gidx = pair_idx;
    g.B = subj_w;  g.bias = subj_b;  g.C = s_mat;
    g.B2 = obj_w;  g.bias2 = obj_b;  g.C2 = o_mat;
    g.M = 256; g.N = 512; g.K = 2048; g.ldc = 712; g.coff = 0; g.kChunk = 2048;
    gemm_k<0><<<dim3(8,4,2), blk, 0, stream>>>(g);
  }
  // embedding concat -> cols [512,712)
  emb_k<<<dim3(400), blk, 0, stream>>>(pair_idx, labels, emb1, emb2, s_mat, o_mat);

  // union 1x1 conv as GEMM -> ubuf[n][oc][q] (scatter epilogue)
  {
    GP g{}; g.A = union_feat; g.B = w_union; g.bias = b_union; g.C = ubuf;
    g.M = 12544; g.N = 256; g.K = 1024; g.kChunk = 1024;
    gemm_k<5><<<dim3(4,196,1), blk, 0, stream>>>(g);
  }

  // conv1 + relu + bn1 -> x1 ; maxpool -> xp
  conv1_k<<<dim3(1792), blk, 0, stream>>>(spatial, conv1_w, conv1_b,
                                          bn1_g, bn1_b, bn1_m, bn1_v, x1);
  pool_k<<<dim3(6272), blk, 0, stream>>>(x1, xp);

  // conv2 (implicit GEMM) + relu + bn2, accumulated into ubuf[n][oc][q]
  {
    GP g{}; g.A = xp; g.B = conv2_w; g.bias = conv2_b; g.C = ubuf;
    g.M = 12544; g.N = 256; g.K = 1152; g.kChunk = 1152;
    g.bn_g = bn2_g; g.bn_b = bn2_b; g.bn_m = bn2_m; g.bn_v = bn2_v;
    gemm_k<6><<<dim3(4,196,1), blk, 0, stream>>>(g);
  }

  // vr linear: split-K 32 -> partials -> rel[:,1424:1936]
  {
    GP g{}; g.A = ubuf; g.B = vr_w; g.C = pvr;
    g.M = 256; g.N = 512; g.K = 12544; g.kChunk = 392;
    gemm_k<2><<<dim3(8,4,32), blk, 0, stream>>>(g);
    reduce_k<<<dim3(512), blk, 0, stream>>>(pvr, vr_b, rel, 32, 256*512, 512, 1936, 1424);
  }

  // lin: concat(s,o) @ lin_w^T, split-K 4 -> partials -> z1
  {
    GP g{}; g.A = s_mat; g.A2 = o_mat; g.B = lin_w; g.C = plin;
    g.M = 256; g.N = 712; g.K = 1424; g.kChunk = 356;
    gemm_k<3><<<dim3(12,4,4), blk, 0, stream>>>(g);
    reduce_k<<<dim3(712), blk, 0, stream>>>(plin, lin_b, z1, 4, 256*712, 712, 712, 0);
  }

  // bilinear: prep (o->bf16, s->sT), barrier-free wave-owned MFMA, split-K 61
  prep_k<<<dim3((256*712 + 712*256 + 255)/256), blk, 0, stream>>>(s_mat, o_mat, obp, sTp);
  bil_mfma_k<<<dim3(12, 2, BILSPLIT), dim3(256), 0, stream>>>(obp, sTp, bil_w, pbil);
  reduce_k<<<dim3(712), blk, 0, stream>>>(pbil, bil_b, bilbuf, BILSPLIT, 256*712, 712, 712, 0);

  // proj: relu(concat(z1,bil)) @ proj_w^T, split-K 2 -> partials -> rel[:,0:1424]
  {
    GP g{}; g.A = z1; g.A2 = bilbuf; g.B = proj_w; g.C = pproj;
    g.M = 256; g.N = 1424; g.K = 1424; g.kChunk = 712;
    gemm_k<4><<<dim3(23,4,2), blk, 0, stream>>>(g);
    reduce_k<<<dim3(1424), blk, 0, stream>>>(pproj, proj_b, rel, 2, 256*1424, 1424, 1936, 0);
  }

  // segments, memory zero + mask, scatter, pooled max
  seg_k<<<dim3(1), blk, 0, stream>>>(im_idx, counts, starts, pos);
  zeromask_k<<<dim3((SZ_MEM + SZ_MASK + 255)/256), blk, 0, stream>>>(out, counts);
  scatter_k<<<dim3(256), blk, 0, stream>>>(rel, pos, im_idx, out);
  pooled_k<<<dim3(8,16), blk, 0, stream>>>(rel, starts, counts, out);

  // act = sigmoid(pooled @ ac_w^T + ac_b)
  {
    GP g{}; g.A = out + OFF_POOLED; g.B = ac_w; g.bias = ac_b; g.C = out + OFF_ACT;
    g.M = 16; g.N = 157; g.K = 1936; g.ldc = 157; g.coff = 0; g.kChunk = 1936;
    gemm_k<8><<<dim3(3,1,1), blk, 0, stream>>>(g);
  }
}

// Round 15
// 2143.726 us; speedup vs baseline: 1.1703x; 1.1703x over previous
//
#include <hip/hip_runtime.h>
#include <math.h>

#define DEV __device__ __forceinline__

// ---- problem constants ----
#define PP    256          // pairs
#define BIMG  16
#define HB    712          // bilinear dim
#define KBIL  (712*712)    // 506944
#define KSTEPS (KBIL/32)   // 15842
#define DRELC 1936
#define BSPLIT 16          // bilinear split-K
#define ZPB    991         // z-steps per split (ceil 15842/16; last = 977)
#define KC     16          // z-steps per staging round (512 k = 2KB/row)
#define SLDS   520         // LDS row stride in bf16 (1040 B: 16B-aligned, 2-way banks)

// ---- d_out layout (floats) ----
#define SZ_ACT    (16*157)
#define OFF_ACT   0
#define OFF_POOLED (SZ_ACT)
#define SZ_POOLED (16*1936)
#define OFF_MEM   (OFF_POOLED + SZ_POOLED)
#define SZ_MEM    (24*16*1936)
#define OFF_MASK  (OFF_MEM + SZ_MEM)
#define SZ_MASK   (16*24)

// ---- ws layout (floats) ----
#define OFF_S     0
#define OFF_O     (OFF_S + 256*712)
#define OFF_Z1    (OFF_O + 256*712)
#define OFF_BIL   (OFF_Z1 + 256*712)
#define OFF_REL   (OFF_BIL + 256*712)
#define OFF_UBUF  (OFF_REL + 256*1936)
#define OFF_XP    (OFF_UBUF + 12544*256)
#define OFF_SHARED (OFF_XP + 256*128*49)
#define OFF_X1    OFF_SHARED                       // 256*128*196 floats
#define OFF_PVR   OFF_SHARED                       // 32*256*512 = 4.19M <= 6.42M
// pbil (16*256*712 = 2.92M floats) aliases ubuf region (dead by then);
// lin/proj partials too, consumed before pbil written (stream-ordered).
#define OFF_PBIL  OFF_UBUF
#define OFF_PLIN  OFF_UBUF
#define OFF_PPROJ OFF_UBUF
#define SZ_SHARED (256*128*196)                    // max(x1, pvr)
#define OFF_INTS  (OFF_SHARED + SZ_SHARED)
// bilinear prep buffers: o as bf16 [256][712], sT f32 [712][256]
#define OFF_OB    (OFF_INTS + 256)                 // 256*712 bf16 = 91136 floats
#define OFF_ST    (OFF_OB + 91136)                 // 712*256 floats

typedef __bf16 bf16x4 __attribute__((ext_vector_type(4)));
typedef __bf16 bf16x8 __attribute__((ext_vector_type(8)));
typedef float  f32x4  __attribute__((ext_vector_type(4)));

// ============================================================
// prep: o -> bf16 (row-major [256][712]); s -> transposed sT [712][256].
// ============================================================
__global__ __launch_bounds__(256) void prep_k(const float* __restrict__ s,
    const float* __restrict__ o, __bf16* __restrict__ ob, float* __restrict__ sT) {
  int i = blockIdx.x*256 + threadIdx.x;
  if (i < 256*712) {
    ob[i] = (__bf16)o[i];
  } else {
    int j = i - 256*712;
    if (j < 712*256) {
      int h = j >> 8, n = j & 255;
      sT[j] = s[n*712 + h];
    }
  }
}

// ============================================================
// Bilinear v3 — DRAM-burst-friendly W access.
// Diagnosis (r5-r14): every variant ran at FETCH/~1.15 TB/s because W was
// read as ~50k concurrent 128B-granule streams (64 rows/block, rows 1.9MB
// apart) -> DRAM row-buffer thrash (~14% of peak).
// Fix: block = 16 cols x 256 rows x split-K16 (grid 45x16). Per round,
// stage 16 rows x 2KB CONTIGUOUS (coalesced 256B/instr) into LDS bf16
// (double-buffered). Compute 16 z-steps/round: 1 ds_read_b128 B-frag
// + 4 rowfrag A-builds (ob bf16 L2-resident, sT coalesced) + 4 MFMA.
// One barrier per round. 1-term bf16 (r12-proven tolerance).
// ============================================================
__global__ __launch_bounds__(256, 3) void bil_mfma_k(
    const __bf16* __restrict__ ob, const float* __restrict__ sT,
    const float* __restrict__ W, float* __restrict__ part) {
  __shared__ __align__(16) __bf16 Wsh[2][16*SLDS];   // 2 x 16.6 KB

  const int tid = threadIdx.x;
  const int wv = tid >> 6, lane = tid & 63;
  const int lr = lane & 15, lg = lane >> 4;
  const int c0 = blockIdx.x * 16;
  const int bz = blockIdx.y;
  const int zbase = bz * ZPB;
  const int zcntT = min(ZPB, KSTEPS - zbase);       // 991 or 977
  const int nrounds = (zcntT + KC - 1) / KC;

  // staging role: 16 threads per col-row; thread reads 8 x float4 (2KB/row total)
  const int srow = tid >> 4;         // 0..15 = col within tile
  const int sl = tid & 15;
  const int scol = min(c0 + srow, 711);
  const float* wrow = W + (size_t)scol * KBIL;

  // compute role: wave wv owns rows [wv*64, wv*64+64), all 16 cols
  const int n0 = wv * 64;
  const int myc = c0 + lr;

  f32x4 acc[4];
  #pragma unroll
  for (int rf = 0; rf < 4; rf++) { acc[rf][0]=0.f; acc[rf][1]=0.f; acc[rf][2]=0.f; acc[rf][3]=0.f; }

  float4 st0, st1, st2, st3, st4, st5, st6, st7;
  auto stage_load = [&](int r) {
    const int kb = (zbase + r*KC) * 32 + sl*4;
    #define LD(J, DST) { int k = kb + (J)*64; if (k > KBIL-4) k = KBIL-4; \
                         DST = *(const float4*)(wrow + k); }
    LD(0, st0) LD(1, st1) LD(2, st2) LD(3, st3)
    LD(4, st4) LD(5, st5) LD(6, st6) LD(7, st7)
    #undef LD
  };
  auto stage_store = [&](int buf) {
    __bf16* base = &Wsh[buf][srow*SLDS + sl*4];
    #define ST(J, SRC) { bf16x4 b; b[0]=(__bf16)SRC.x; b[1]=(__bf16)SRC.y; \
                         b[2]=(__bf16)SRC.z; b[3]=(__bf16)SRC.w; \
                         *(bf16x4*)(base + (J)*64) = b; }
    ST(0, st0) ST(1, st1) ST(2, st2) ST(3, st3)
    ST(4, st4) ST(5, st5) ST(6, st6) ST(7, st7)
    #undef ST
  };

  // ---- prologue ----
  stage_load(0);
  stage_store(0);
  if (nrounds > 1) stage_load(1);
  __syncthreads();

  // ---- main loop: one barrier per 16-step round ----
  for (int r = 0; r < nrounds; ++r) {
    const int zr0 = zbase + r*KC;
    const int zc = min(KC, zbase + zcntT - zr0);
    const int buf = r & 1;
    for (int zs = 0; zs < zc; ++zs) {
      bf16x8 b8 = *(const bf16x8*)&Wsh[buf][lr*SLDS + zs*32 + lg*8];
      const int kk = (zr0 + zs)*32 + lg*8;
      const int h = kk / 712;
      const int t = kk - h*712;                     // multiple of 8, <= 704
      #pragma unroll
      for (int rf = 0; rf < 4; rf++) {
        const int n = n0 + rf*16 + lr;
        bf16x8 o8 = *(const bf16x8*)&ob[(size_t)n*712 + t];
        const float sv = sT[h*256 + n];
        bf16x8 a8;
        #pragma unroll
        for (int i = 0; i < 8; i++) a8[i] = (__bf16)(sv * (float)o8[i]);
        acc[rf] = __builtin_amdgcn_mfma_f32_16x16x32_bf16(a8, b8, acc[rf], 0, 0, 0);
      }
    }
    if (r + 1 < nrounds) {
      stage_store((r+1)&1);          // writes buffer NOT being computed
      __syncthreads();
      if (r + 2 < nrounds) stage_load(r+2);
    }
  }

  // ---- epilogue: partials [bz][256][712] (D: col=lane&15, row=(lane>>4)*4+i)
  if (myc < 712) {
    #pragma unroll
    for (int rf = 0; rf < 4; rf++) {
      #pragma unroll
      for (int i = 0; i < 4; i++) {
        const int n = n0 + rf*16 + lg*4 + i;
        part[((size_t)bz*256 + n)*712 + myc] = acc[rf][i];
      }
    }
  }
}

struct GP {
  const float* A; const float* A2; const float* B; const float* bias;
  float* C;
  const int* gidx; int goff;
  int M, N, K;
  int ldc, coff;
  int kChunk;
  const float* bn_g; const float* bn_b; const float* bn_m; const float* bn_v;
  const float* B2; const float* bias2; float* C2;   // mode 0 pair-merge
};

// modes:
// 0: A gathered via gidx col=blockIdx.z; B/bias/C selected by blockIdx.z
// 2: plain A (ubuf rows), plain B (vr_w)        epi: partial C[z][M][N]
// 3: A = concat(s,o)                            epi: partial C[z][M][N]
// 4: A = relu(concat(z1,bil))                   epi: partial C[z][M][N]
// 5: A = union_feat gather [(n,q)][ic]          epi: +bias -> ubuf[n][oc][q]
// 6: A = im2col(xp) 3x3 pad1                    epi: bn2(relu(+bias)) += ubuf[n][oc][q]
// 8: plain A                                    epi: sigmoid(+bias) -> C

template<int MODE>
DEV float loadA(const GP& p, int r, int k) {
  if (MODE == 0) { int fr = p.gidx[2*r + (int)blockIdx.z]; return p.A[fr*2048 + k]; }
  if (MODE == 2 || MODE == 8) return p.A[r*p.K + k];
  if (MODE == 3) return (k < 712) ? p.A[r*712 + k] : p.A2[r*712 + (k-712)];
  if (MODE == 4) { float v = (k < 712) ? p.A[r*712 + k] : p.A2[r*712 + (k-712)];
                   return fmaxf(v, 0.f); }
  if (MODE == 5) { int n = r/49, q = r - n*49; return p.A[(n*1024 + k)*49 + q]; }
  if (MODE == 6) {
    int n = r/49, q = r - n*49; int py = q/7, px = q - py*7;
    int ic = k/9, k9 = k - ic*9; int dy = k9/3, dx = k9 - dy*3;
    int iy = py + dy - 1, ix = px + dx - 1;
    if ((unsigned)iy >= 7u || (unsigned)ix >= 7u) return 0.f;
    return p.A[(n*128 + ic)*49 + iy*7 + ix];
  }
  return 0.f;
}

template<int MODE>
DEV float loadB(const GP& p, int c, int k) {
  if (MODE == 0) { const float* Bp = blockIdx.z ? p.B2 : p.B; return Bp[c*p.K + k]; }
  return p.B[c*p.K + k];
}

// ============================================================
// Generic GEMM, bf16-split MFMA (3-term, unchanged from r10-r13).
// ============================================================
template<int MODE>
__global__ __launch_bounds__(256) void gemm_k(GP p) {
  __shared__ __align__(16) __bf16 Ash[2][64*44];
  __shared__ __align__(16) __bf16 Bsh[2][64*44];
  const int tid = threadIdx.x;
  const int srow = tid & 63, koff = (tid >> 6) * 8;
  const int col0 = blockIdx.x * 64, row0 = blockIdx.y * 64;
  const int kStart = (MODE == 0) ? 0 : blockIdx.z * p.kChunk;
  const int kEnd = min(p.K, kStart + p.kChunk);
  const int wv = tid >> 6, lane = tid & 63;
  const int lr = lane & 15, lg = lane >> 4;
  const int rh = wv >> 1, ch = wv & 1;

  f32x4 acc[2][2];
  #pragma unroll
  for (int a = 0; a < 2; a++)
    #pragma unroll
    for (int b = 0; b < 2; b++) { acc[a][b][0]=0.f; acc[a][b][1]=0.f; acc[a][b][2]=0.f; acc[a][b][3]=0.f; }

  for (int kb = kStart; kb < kEnd; kb += 32) {
    {
      const int gr = row0 + srow;
      float v[8];
      #pragma unroll
      for (int i = 0; i < 8; i++) {
        const int gk = kb + koff + i;
        v[i] = (gr < p.M && gk < kEnd) ? loadA<MODE>(p, gr, gk) : 0.f;
      }
      bf16x8 hi, lo;
      #pragma unroll
      for (int i = 0; i < 8; i++) {
        __bf16 h = (__bf16)v[i];
        hi[i] = h;
        lo[i] = (__bf16)(v[i] - (float)h);
      }
      *(bf16x8*)&Ash[0][srow*44 + koff] = hi;
      *(bf16x8*)&Ash[1][srow*44 + koff] = lo;
    }
    {
      const int gc = col0 + srow;
      float v[8];
      #pragma unroll
      for (int i = 0; i < 8; i++) {
        const int gk = kb + koff + i;
        v[i] = (gc < p.N && gk < kEnd) ? loadB<MODE>(p, gc, gk) : 0.f;
      }
      bf16x8 hi, lo;
      #pragma unroll
      for (int i = 0; i < 8; i++) {
        __bf16 h = (__bf16)v[i];
        hi[i] = h;
        lo[i] = (__bf16)(v[i] - (float)h);
      }
      *(bf16x8*)&Bsh[0][srow*44 + koff] = hi;
      *(bf16x8*)&Bsh[1][srow*44 + koff] = lo;
    }
    __syncthreads();
    #pragma unroll
    for (int rf = 0; rf < 2; rf++) {
      bf16x8 ahi = *(const bf16x8*)&Ash[0][(rh*32 + rf*16 + lr)*44 + lg*8];
      bf16x8 alo = *(const bf16x8*)&Ash[1][(rh*32 + rf*16 + lr)*44 + lg*8];
      #pragma unroll
      for (int cf = 0; cf < 2; cf++) {
        bf16x8 bhi = *(const bf16x8*)&Bsh[0][(ch*32 + cf*16 + lr)*44 + lg*8];
        bf16x8 blo = *(const bf16x8*)&Bsh[1][(ch*32 + cf*16 + lr)*44 + lg*8];
        acc[rf][cf] = __builtin_amdgcn_mfma_f32_16x16x32_bf16(ahi, bhi, acc[rf][cf], 0, 0, 0);
        acc[rf][cf] = __builtin_amdgcn_mfma_f32_16x16x32_bf16(ahi, blo, acc[rf][cf], 0, 0, 0);
        acc[rf][cf] = __builtin_amdgcn_mfma_f32_16x16x32_bf16(alo, bhi, acc[rf][cf], 0, 0, 0);
      }
    }
    __syncthreads();
  }

  // ---- epilogue (D: col=lane&15, row=(lane>>4)*4+i) ----
  #pragma unroll
  for (int rf = 0; rf < 2; rf++) {
    #pragma unroll
    for (int cf = 0; cf < 2; cf++) {
      const int c = col0 + ch*32 + cf*16 + lr;
      if (c >= p.N) continue;
      #pragma unroll
      for (int i = 0; i < 4; i++) {
        const int r = row0 + rh*32 + rf*16 + lg*4 + i;
        if (r >= p.M) continue;
        float v = acc[rf][cf][i];
        if (MODE == 2 || MODE == 3 || MODE == 4) {
          p.C[(size_t)blockIdx.z * p.M * p.N + (size_t)r * p.N + c] = v;
        } else if (MODE == 5) {
          int n = r/49, q = r - n*49;
          p.C[n*12544 + c*49 + q] = v + p.bias[c];
        } else if (MODE == 6) {
          int n = r/49, q = r - n*49;
          float sc = p.bn_g[c] / sqrtf(p.bn_v[c] + 1e-5f);
          float sh = p.bn_b[c] - p.bn_m[c]*sc;
          float t2 = fmaxf(v + p.bias[c], 0.f)*sc + sh;
          p.C[n*12544 + c*49 + q] += t2;
        } else if (MODE == 8) {
          float t2 = v + p.bias[c];
          p.C[r*p.ldc + p.coff + c] = 1.f/(1.f + expf(-t2));
        } else {  // MODE 0: pair-merged subj/obj
          const float* bb = blockIdx.z ? p.bias2 : p.bias;
          float* Cp = blockIdx.z ? p.C2 : p.C;
          Cp[r*p.ldc + p.coff + c] = v + bb[c];
        }
      }
    }
  }
}

__global__ __launch_bounds__(256) void reduce_k(const float* __restrict__ part,
    const float* __restrict__ bias, float* __restrict__ out,
    int S, int MN, int N, int ldc, int coff) {
  int i = blockIdx.x*256 + threadIdx.x;
  if (i >= MN) return;
  float s = 0.f;
  for (int z = 0; z < S; z++) s += part[(size_t)z*MN + i];
  int r = i / N, c = i - r*N;
  out[r*ldc + coff + c] = s + bias[c];
}

__global__ __launch_bounds__(256) void emb_k(const int* __restrict__ pi,
    const int* __restrict__ labels, const float* __restrict__ e1,
    const float* __restrict__ e2, float* __restrict__ s, float* __restrict__ o) {
  int i = blockIdx.x*256 + threadIdx.x;
  if (i >= 2*256*200) return;
  int which = i / (256*200); int rest = i - which*(256*200);
  int n = rest / 200; int j = rest - n*200;
  int lab = labels[pi[2*n + which]];
  float v = which ? e2[lab*200 + j] : e1[lab*200 + j];
  (which ? o : s)[n*712 + 512 + j] = v;
}

__global__ __launch_bounds__(256) void conv1_k(const float* __restrict__ in,
    const float* __restrict__ w, const float* __restrict__ bias,
    const float* __restrict__ g, const float* __restrict__ bt,
    const float* __restrict__ m, const float* __restrict__ vv,
    float* __restrict__ out) {
  int idx = blockIdx.x*256 + threadIdx.x;
  if (idx >= 256*128*14) return;
  int oy = idx % 14; int t = idx / 14; int c = t & 127; int n = t >> 7;
  float acc[14];
  float b0 = bias[c];
  #pragma unroll
  for (int ox = 0; ox < 14; ox++) acc[ox] = b0;
  for (int ci = 0; ci < 2; ci++) {
    #pragma unroll
    for (int ky = 0; ky < 7; ky++) {
      int iy = oy*2 - 3 + ky;
      if ((unsigned)iy >= 27u) continue;
      const float* ir = in + ((n*2 + ci)*27 + iy)*27;
      const float* wr = w + ((c*2 + ci)*7 + ky)*7;
      float iv[27];
      #pragma unroll
      for (int x = 0; x < 27; x++) iv[x] = ir[x];
      float wk[7];
      #pragma unroll
      for (int kx = 0; kx < 7; kx++) wk[kx] = wr[kx];
      #pragma unroll
      for (int kx = 0; kx < 7; kx++)
        #pragma unroll
        for (int ox = 0; ox < 14; ox++) {
          int ix = ox*2 - 3 + kx;
          if (ix >= 0 && ix < 27) acc[ox] += iv[ix]*wk[kx];
        }
    }
  }
  float sc = g[c] / sqrtf(vv[c] + 1e-5f);
  float sh = bt[c] - m[c]*sc;
  float* orow = out + ((n*128 + c)*14 + oy)*14;
  #pragma unroll
  for (int ox = 0; ox < 14; ox++) orow[ox] = fmaxf(acc[ox], 0.f)*sc + sh;
}

__global__ __launch_bounds__(256) void pool_k(const float* __restrict__ x1,
                                              float* __restrict__ xp) {
  int idx = blockIdx.x*256 + threadIdx.x;
  if (idx >= 256*128*49) return;
  int px = idx % 7; int t = idx / 7; int py = t % 7; t /= 7;
  int c = t & 127; int n = t >> 7;
  float mx = -INFINITY;
  for (int dy = 0; dy < 3; dy++) {
    int y = py*2 - 1 + dy;
    if ((unsigned)y >= 14u) continue;
    for (int dx = 0; dx < 3; dx++) {
      int x = px*2 - 1 + dx;
      if ((unsigned)x >= 14u) continue;
      mx = fmaxf(mx, x1[((n*128 + c)*14 + y)*14 + x]);
    }
  }
  xp[((n*128 + c)*7 + py)*7 + px] = mx;
}

__global__ __launch_bounds__(256) void seg_k(const int* __restrict__ im,
    int* __restrict__ counts, int* __restrict__ starts, int* __restrict__ pos) {
  __shared__ int c[16], s[16];
  int tid = threadIdx.x;
  if (tid < 16) c[tid] = 0;
  __syncthreads();
  atomicAdd(&c[im[tid]], 1);
  __syncthreads();
  if (tid == 0) { int run = 0; for (int b = 0; b < 16; b++) { s[b] = run; run += c[b]; } }
  __syncthreads();
  if (tid < 16) { counts[tid] = c[tid]; starts[tid] = s[tid]; }
  pos[tid] = tid - s[im[tid]];
}

__global__ __launch_bounds__(256) void zeromask_k(float* __restrict__ out,
                                                  const int* __restrict__ counts) {
  int i = blockIdx.x*256 + threadIdx.x;
  if (i < SZ_MEM) { out[OFF_MEM + i] = 0.f; return; }
  int j = i - SZ_MEM;
  if (j < SZ_MASK) {
    int b = j / 24, l = j - b*24;
    out[OFF_MASK + j] = (l >= counts[b]) ? 1.f : 0.f;
  }
}

__global__ __launch_bounds__(256) void scatter_k(const float* __restrict__ rel,
    const int* __restrict__ pos, const int* __restrict__ im, float* __restrict__ out) {
  int n = blockIdx.x;
  int l = pos[n], b = im[n];
  float* dst = out + OFF_MEM + ((size_t)l*16 + b)*1936;
  const float* src = rel + (size_t)n*1936;
  for (int d = threadIdx.x; d < 1936; d += 256) dst[d] = src[d];
}

__global__ __launch_bounds__(256) void pooled_k(const float* __restrict__ rel,
    const int* __restrict__ starts, const int* __restrict__ counts,
    float* __restrict__ out) {
  int b = blockIdx.y;
  int d = blockIdx.x*256 + threadIdx.x;
  if (d >= 1936) return;
  int st = starts[b], ct = counts[b];
  float mx = -INFINITY;
  for (int i = 0; i < ct; i++) mx = fmaxf(mx, rel[(size_t)(st + i)*1936 + d]);
  out[OFF_POOLED + b*1936 + d] = mx;
}

extern "C" void kernel_launch(void* const* d_in, const int* in_sizes, int n_in,
                              void* d_out, int out_size, void* d_ws, size_t ws_size,
                              hipStream_t stream) {
  const float* features   = (const float*)d_in[0];
  const int*   pair_idx   = (const int*)d_in[1];
  const int*   im_idx     = (const int*)d_in[2];
  const int*   labels     = (const int*)d_in[3];
  const float* union_feat = (const float*)d_in[4];
  const float* spatial    = (const float*)d_in[5];
  const float* w_union    = (const float*)d_in[6];
  const float* b_union    = (const float*)d_in[7];
  const float* conv1_w    = (const float*)d_in[8];
  const float* conv1_b    = (const float*)d_in[9];
  const float* bn1_g      = (const float*)d_in[10];
  const float* bn1_b      = (const float*)d_in[11];
  const float* bn1_m      = (const float*)d_in[12];
  const float* bn1_v      = (const float*)d_in[13];
  const float* conv2_w    = (const float*)d_in[14];
  const float* conv2_b    = (const float*)d_in[15];
  const float* bn2_g      = (const float*)d_in[16];
  const float* bn2_b      = (const float*)d_in[17];
  const float* bn2_m      = (const float*)d_in[18];
  const float* bn2_v      = (const float*)d_in[19];
  const float* subj_w     = (const float*)d_in[20];
  const float* subj_b     = (const float*)d_in[21];
  const float* obj_w      = (const float*)d_in[22];
  const float* obj_b      = (const float*)d_in[23];
  const float* vr_w       = (const float*)d_in[24];
  const float* vr_b       = (const float*)d_in[25];
  const float* emb1       = (const float*)d_in[26];
  const float* emb2       = (const float*)d_in[27];
  const float* bil_w      = (const float*)d_in[28];
  const float* bil_b      = (const float*)d_in[29];
  const float* lin_w      = (const float*)d_in[30];
  const float* lin_b      = (const float*)d_in[31];
  const float* proj_w     = (const float*)d_in[32];
  const float* proj_b     = (const float*)d_in[33];
  const float* ac_w       = (const float*)d_in[34];
  const float* ac_b       = (const float*)d_in[35];

  float* ws = (float*)d_ws;
  float* s_mat  = ws + OFF_S;
  float* o_mat  = ws + OFF_O;
  float* z1     = ws + OFF_Z1;
  float* bilbuf = ws + OFF_BIL;
  float* rel    = ws + OFF_REL;
  float* ubuf   = ws + OFF_UBUF;   // layout [n][oc][q] = [256][256][49]
  float* x1     = ws + OFF_X1;
  float* xp     = ws + OFF_XP;
  float* pvr    = ws + OFF_PVR;
  float* pbil   = ws + OFF_PBIL;
  float* plin   = ws + OFF_PLIN;
  float* pproj  = ws + OFF_PPROJ;
  int*   ints   = (int*)(ws + OFF_INTS);
  __bf16* obp   = (__bf16*)(ws + OFF_OB);
  float* sTp    = ws + OFF_ST;
  int* counts = ints; int* starts = ints + 16; int* pos = ints + 32;
  float* out = (float*)d_out;

  dim3 blk(256);

  // subj + obj linears in ONE dispatch (blockIdx.z selects weights/output)
  {
    GP g{}; g.A = features; g.gidx = pair_idx;
    g.B = subj_w;  g.bias = subj_b;  g.C = s_mat;
    g.B2 = obj_w;  g.bias2 = obj_b;  g.C2 = o_mat;
    g.M = 256; g.N = 512; g.K = 2048; g.ldc = 712; g.coff = 0; g.kChunk = 2048;
    gemm_k<0><<<dim3(8,4,2), blk, 0, stream>>>(g);
  }
  // embedding concat -> cols [512,712)
  emb_k<<<dim3(400), blk, 0, stream>>>(pair_idx, labels, emb1, emb2, s_mat, o_mat);

  // union 1x1 conv as GEMM -> ubuf[n][oc][q] (scatter epilogue)
  {
    GP g{}; g.A = union_feat; g.B = w_union; g.bias = b_union; g.C = ubuf;
    g.M = 12544; g.N = 256; g.K = 1024; g.kChunk = 1024;
    gemm_k<5><<<dim3(4,196,1), blk, 0, stream>>>(g);
  }

  // conv1 + relu + bn1 -> x1 ; maxpool -> xp
  conv1_k<<<dim3(1792), blk, 0, stream>>>(spatial, conv1_w, conv1_b,
                                          bn1_g, bn1_b, bn1_m, bn1_v, x1);
  pool_k<<<dim3(6272), blk, 0, stream>>>(x1, xp);

  // conv2 (implicit GEMM) + relu + bn2, accumulated into ubuf[n][oc][q]
  {
    GP g{}; g.A = xp; g.B = conv2_w; g.bias = conv2_b; g.C = ubuf;
    g.M = 12544; g.N = 256; g.K = 1152; g.kChunk = 1152;
    g.bn_g = bn2_g; g.bn_b = bn2_b; g.bn_m = bn2_m; g.bn_v = bn2_v;
    gemm_k<6><<<dim3(4,196,1), blk, 0, stream>>>(g);
  }

  // vr linear: split-K 32 -> partials -> rel[:,1424:1936]
  {
    GP g{}; g.A = ubuf; g.B = vr_w; g.C = pvr;
    g.M = 256; g.N = 512; g.K = 12544; g.kChunk = 392;
    gemm_k<2><<<dim3(8,4,32), blk, 0, stream>>>(g);
    reduce_k<<<dim3(512), blk, 0, stream>>>(pvr, vr_b, rel, 32, 256*512, 512, 1936, 1424);
  }

  // lin: concat(s,o) @ lin_w^T, split-K 4 -> partials -> z1
  {
    GP g{}; g.A = s_mat; g.A2 = o_mat; g.B = lin_w; g.C = plin;
    g.M = 256; g.N = 712; g.K = 1424; g.kChunk = 356;
    gemm_k<3><<<dim3(12,4,4), blk, 0, stream>>>(g);
    reduce_k<<<dim3(712), blk, 0, stream>>>(plin, lin_b, z1, 4, 256*712, 712, 712, 0);
  }

  // bilinear: prep, burst-staged MFMA (16 cols x 256 rows x split-K 16)
  prep_k<<<dim3((256*712 + 712*256 + 255)/256), blk, 0, stream>>>(s_mat, o_mat, obp, sTp);
  bil_mfma_k<<<dim3(45, BSPLIT), blk, 0, stream>>>(obp, sTp, bil_w, pbil);
  reduce_k<<<dim3(712), blk, 0, stream>>>(pbil, bil_b, bilbuf, BSPLIT, 256*712, 712, 712, 0);

  // proj: relu(concat(z1,bil)) @ proj_w^T, split-K 2 -> partials -> rel[:,0:1424]
  {
    GP g{}; g.A = z1; g.A2 = bilbuf; g.B = proj_w; g.C = pproj;
    g.M = 256; g.N = 1424; g.K = 1424; g.kChunk = 712;
    gemm_k<4><<<dim3(23,4,2), blk, 0, stream>>>(g);
    reduce_k<<<dim3(1424), blk, 0, stream>>>(pproj, proj_b, rel, 2, 256*1424, 1424, 1936, 0);
  }

  // segments, memory zero + mask, scatter, pooled max
  seg_k<<<dim3(1), blk, 0, stream>>>(im_idx, counts, starts, pos);
  zeromask_k<<<dim3((SZ_MEM + SZ_MASK + 255)/256), blk, 0, stream>>>(out, counts);
  scatter_k<<<dim3(256), blk, 0, stream>>>(rel, pos, im_idx, out);
  pooled_k<<<dim3(8,16), blk, 0, stream>>>(rel, starts, counts, out);

  // act = sigmoid(pooled @ ac_w^T + ac_b)
  {
    GP g{}; g.A = out + OFF_POOLED; g.B = ac_w; g.bias = ac_b; g.C = out + OFF_ACT;
    g.M = 16; g.N = 157; g.K = 1936; g.ldc = 157; g.coff = 0; g.kChunk = 1936;
    gemm_k<8><<<dim3(3,1,1), blk, 0, stream>>>(g);
  }
}